// Round 6
// baseline (104.933 us; speedup 1.0000x reference)
//
#include <hip/hip_runtime.h>

// out = tanh(y @ W1^T + b1) @ W2^T + b2
// y:[B,2] f32, W1:[50,2], b1:[50], W2:[2,50], b2:[2], out:[B,2] f32, B=2e6
//
// Folded form (prep kernel writes to ws):
//   wa[j] = W1[j][0]*2log2e, wb[j] = W1[j][1]*2log2e, wc[j] = b1[j]*2log2e
//   va[j] = -2*W2[0][j],     vb[j] = -2*W2[1][j]
//   s0 = b2[0] + sum_j W2[0][j], s1 = b2[1] + sum_j W2[1][j]
// Then per row: e = exp2(wa*y0 + wb*y1 + wc); r = rcp(e+1)
//   out0 = s0 + sum va[j]*r_j ; out1 = s1 + sum vb[j]*r_j
// (tanh(z) = 1 - 2/(exp(2z)+1); the "1" sums into s, the "-2" folds into v.)

#define NROWS 2000000
#define HID 50
#define C2L 2.8853900817779268f  // 2*log2(e)

// ws float layout: wa[64] | wb[64] | wc[64] | va[64] | vb[64] | s0 s1
__global__ void prep_kernel(const float* __restrict__ W1, const float* __restrict__ b1,
                            const float* __restrict__ W2, const float* __restrict__ b2,
                            float* __restrict__ w) {
    const int j = threadIdx.x;  // single block of 64
    float wa = 0.f, wb = 0.f, wc = 0.f, va = 0.f, vb = 0.f;
    float t0 = 0.f, t1 = 0.f;
    if (j < HID) {
        wa = W1[2 * j] * C2L;
        wb = W1[2 * j + 1] * C2L;
        wc = b1[j] * C2L;
        t0 = W2[j];
        t1 = W2[HID + j];
        va = -2.0f * t0;
        vb = -2.0f * t1;
    }
    // zero-padded through j=63 so the main loop can run j=0..55 safely
    w[j] = wa; w[64 + j] = wb; w[128 + j] = wc; w[192 + j] = va; w[256 + j] = vb;
#pragma unroll
    for (int off = 32; off > 0; off >>= 1) {
        t0 += __shfl_down(t0, off, 64);
        t1 += __shfl_down(t1, off, 64);
    }
    if (j == 0) { w[320] = b2[0] + t0; w[321] = b2[1] + t1; }
}

__global__ __launch_bounds__(256) void ode_main(const float* __restrict__ y,
                                                const float* __restrict__ w,
                                                float* __restrict__ out) {
    const int tid = blockIdx.x * 256 + threadIdx.x;
    if (tid >= NROWS / 2) return;

    // two rows per thread: one coalesced float4 in, one float4 out
    const float4 yv = reinterpret_cast<const float4*>(y)[tid];
    const float y0a = yv.x, y0b = yv.y;   // row 0
    const float y1a = yv.z, y1b = yv.w;   // row 1

    float o00 = w[320], o01 = w[321];
    float o10 = o00,    o11 = o01;

#pragma unroll
    for (int c = 0; c < 56; c += 8) {
        float wa[8], wb_[8], wc_[8], va[8], vb[8];
        *(float4*)&wa[0]  = *(const float4*)(w + c);
        *(float4*)&wa[4]  = *(const float4*)(w + c + 4);
        *(float4*)&wb_[0] = *(const float4*)(w + 64 + c);
        *(float4*)&wb_[4] = *(const float4*)(w + 64 + c + 4);
        *(float4*)&wc_[0] = *(const float4*)(w + 128 + c);
        *(float4*)&wc_[4] = *(const float4*)(w + 128 + c + 4);
        *(float4*)&va[0]  = *(const float4*)(w + 192 + c);
        *(float4*)&va[4]  = *(const float4*)(w + 192 + c + 4);
        *(float4*)&vb[0]  = *(const float4*)(w + 256 + c);
        *(float4*)&vb[4]  = *(const float4*)(w + 256 + c + 4);
#pragma unroll
        for (int k = 0; k < 8; ++k) {
            float z0 = fmaf(wa[k], y0a, fmaf(wb_[k], y0b, wc_[k]));
            float z1 = fmaf(wa[k], y1a, fmaf(wb_[k], y1b, wc_[k]));
            float e0 = __builtin_amdgcn_exp2f(z0);
            float e1 = __builtin_amdgcn_exp2f(z1);
            float r0 = __builtin_amdgcn_rcpf(e0 + 1.0f);
            float r1 = __builtin_amdgcn_rcpf(e1 + 1.0f);
            o00 = fmaf(va[k], r0, o00);
            o01 = fmaf(vb[k], r0, o01);
            o10 = fmaf(va[k], r1, o10);
            o11 = fmaf(vb[k], r1, o11);
        }
    }

    float4 s; s.x = o00; s.y = o01; s.z = o10; s.w = o11;
    reinterpret_cast<float4*>(out)[tid] = s;
}

extern "C" void kernel_launch(void* const* d_in, const int* in_sizes, int n_in,
                              void* d_out, int out_size, void* d_ws, size_t ws_size,
                              hipStream_t stream) {
    // setup_inputs order: t, y, W1, b1, W2, b2
    const float* y  = (const float*)d_in[1];
    const float* W1 = (const float*)d_in[2];
    const float* b1 = (const float*)d_in[3];
    const float* W2 = (const float*)d_in[4];
    const float* b2 = (const float*)d_in[5];
    float* out = (float*)d_out;
    float* w   = (float*)d_ws;   // needs 322 floats; ws is far larger

    prep_kernel<<<1, 64, 0, stream>>>(W1, b1, W2, b2, w);

    const int threads = NROWS / 2;                 // 1,000,000
    const int grid = (threads + 255) / 256;        // 3907
    ode_main<<<grid, 256, 0, stream>>>(y, w, out);
}

// Round 8
// 102.435 us; speedup vs baseline: 1.0244x; 1.0244x over previous
//
#include <hip/hip_runtime.h>

// out = tanh(y @ W1^T + b1) @ W2^T + b2
// y:[B,2] f32, W1:[50,2], b1:[50], W2:[2,50], b2:[2], out:[B,2] f32, B=2e6
//
// Packed-f32 variant: each thread owns 2 rows, carried in the two lanes of
// f32x2 so the z/accumulate FMAs emit v_pk_fma_f32 (gfx90a+ packed fp32).
// Folded weights are stored DUPLICATED (w[2j]==w[2j+1]) so a uniform 64-bit
// load is already the {w,w} splat a packed op needs.
//   wa[j] = W1[j][0]*2log2e, wb[j] = W1[j][1]*2log2e, wc[j] = b1[j]*2log2e
//   va[j] = -2*W2[0][j],     vb[j] = -2*W2[1][j]
//   s0 = b2[0] + sum_j W2[0][j], s1 = b2[1] + sum_j W2[1][j]
// tanh(z) = 1 - 2/(exp2(z*2log2e)+1); "1" folds into s, "-2" into v.

typedef float f32x2 __attribute__((ext_vector_type(2)));

#define NROWS 2000000
#define HID 50
#define C2L 2.8853900817779268f  // 2*log2(e)

// ws float layout (duplicated pairs, 512B-aligned arrays):
// wa2[112] @0 | wb2[112] @128 | wc2[112] @256 | va2[112] @384 | vb2[112] @512 | s0,s1 @640
__global__ void prep_kernel(const float* __restrict__ W1, const float* __restrict__ b1,
                            const float* __restrict__ W2, const float* __restrict__ b2,
                            float* __restrict__ w) {
    const int j = threadIdx.x;  // single block of 64
    float wa = 0.f, wb = 0.f, wc = 0.f, va = 0.f, vb = 0.f;
    float t0 = 0.f, t1 = 0.f;
    if (j < HID) {
        wa = W1[2 * j] * C2L;
        wb = W1[2 * j + 1] * C2L;
        wc = b1[j] * C2L;
        t0 = W2[j];
        t1 = W2[HID + j];
        va = -2.0f * t0;
        vb = -2.0f * t1;
    }
    if (j < 56) {  // zero-padded through j=55 so the main loop runs j=0..55
        w[2 * j] = wa;        w[2 * j + 1] = wa;
        w[128 + 2 * j] = wb;  w[128 + 2 * j + 1] = wb;
        w[256 + 2 * j] = wc;  w[256 + 2 * j + 1] = wc;
        w[384 + 2 * j] = va;  w[384 + 2 * j + 1] = va;
        w[512 + 2 * j] = vb;  w[512 + 2 * j + 1] = vb;
    }
#pragma unroll
    for (int off = 32; off > 0; off >>= 1) {
        t0 += __shfl_down(t0, off, 64);
        t1 += __shfl_down(t1, off, 64);
    }
    if (j == 0) { w[640] = b2[0] + t0; w[641] = b2[1] + t1; }
}

__global__ __launch_bounds__(256) void ode_main(const float* __restrict__ y,
                                                const float* __restrict__ w,
                                                float* __restrict__ out) {
    const int tid = blockIdx.x * 256 + threadIdx.x;
    if (tid >= NROWS / 2) return;

    // two rows per thread: one coalesced float4 in, one float4 out
    const float4 yv = reinterpret_cast<const float4*>(y)[tid];
    const f32x2 ya = {yv.x, yv.z};   // y[:,0] of rows (2t, 2t+1)
    const f32x2 yb = {yv.y, yv.w};   // y[:,1]

    f32x2 o0 = {w[640], w[640]};
    f32x2 o1 = {w[641], w[641]};

    const f32x2* wa2 = (const f32x2*)(w);
    const f32x2* wb2 = (const f32x2*)(w + 128);
    const f32x2* wc2 = (const f32x2*)(w + 256);
    const f32x2* va2 = (const f32x2*)(w + 384);
    const f32x2* vb2 = (const f32x2*)(w + 512);

#pragma unroll
    for (int j = 0; j < 56; ++j) {
        // z = wa*y0 + wb*y1 + wc  (two rows packed) -> 2x v_pk_fma_f32
        f32x2 z = __builtin_elementwise_fma(
            wa2[j], ya, __builtin_elementwise_fma(wb2[j], yb, wc2[j]));
        f32x2 e;
        e.x = __builtin_amdgcn_exp2f(z.x);   // trans pipe, scalar only
        e.y = __builtin_amdgcn_exp2f(z.y);
        f32x2 ep = e + (f32x2){1.0f, 1.0f};  // v_pk_add_f32
        f32x2 r;
        r.x = __builtin_amdgcn_rcpf(ep.x);
        r.y = __builtin_amdgcn_rcpf(ep.y);
        o0 = __builtin_elementwise_fma(va2[j], r, o0);  // v_pk_fma_f32
        o1 = __builtin_elementwise_fma(vb2[j], r, o1);
        // padded j=50..55: wa=wb=wc=0 -> r=0.5, va=vb=0 -> no contribution
    }

    float4 s; s.x = o0.x; s.y = o1.x; s.z = o0.y; s.w = o1.y;
    reinterpret_cast<float4*>(out)[tid] = s;
}

extern "C" void kernel_launch(void* const* d_in, const int* in_sizes, int n_in,
                              void* d_out, int out_size, void* d_ws, size_t ws_size,
                              hipStream_t stream) {
    // setup_inputs order: t, y, W1, b1, W2, b2
    const float* y  = (const float*)d_in[1];
    const float* W1 = (const float*)d_in[2];
    const float* b1 = (const float*)d_in[3];
    const float* W2 = (const float*)d_in[4];
    const float* b2 = (const float*)d_in[5];
    float* out = (float*)d_out;
    float* w   = (float*)d_ws;   // needs 642 floats; ws is far larger

    prep_kernel<<<1, 64, 0, stream>>>(W1, b1, W2, b2, w);

    const int threads = NROWS / 2;                 // 1,000,000
    const int grid = (threads + 255) / 256;        // 3907
    ode_main<<<grid, 256, 0, stream>>>(y, w, out);
}

// Round 9
// 100.495 us; speedup vs baseline: 1.0442x; 1.0193x over previous
//
#include <hip/hip_runtime.h>

// out = tanh(y @ W1^T + b1) @ W2^T + b2
// y:[B,2] f32, W1:[50,2], b1:[50], W2:[2,50], b2:[2], out:[B,2] f32, B=2e6
//
// Packed-f32 + Montgomery-batched reciprocals.
// Each thread owns 2 rows carried in f32x2 lanes (v_pk_fma_f32).
// tanh(z) = 1 - 2/(exp2(2log2e*z)+1); "1" folds into s, "-2" into v:
//   out = s + sum_j v[j] * r_j,  r_j = 1/(e_j+1)
// Montgomery trick per group of 4 j's: 1 v_rcp_f32 instead of 4
// (prefix products + backward unwind, 9 pk_mul per group).
// Weights stored DUPLICATED (w[2j]==w[2j+1]) so uniform 64-bit loads are
// ready {w,w} splats for packed ops.

typedef float f32x2 __attribute__((ext_vector_type(2)));

#define NROWS 2000000
#define HID 50
#define NJ 52          // HID padded to multiple of 4
#define C2L 2.8853900817779268f  // 2*log2(e)

// ws float layout (duplicated pairs):
// wa2[112] @0 | wb2[112] @128 | wc2[112] @256 | va2[112] @384 | vb2[112] @512 | s0,s1 @640
__global__ void prep_kernel(const float* __restrict__ W1, const float* __restrict__ b1,
                            const float* __restrict__ W2, const float* __restrict__ b2,
                            float* __restrict__ w) {
    const int j = threadIdx.x;  // single block of 64
    float wa = 0.f, wb = 0.f, wc = 0.f, va = 0.f, vb = 0.f;
    float t0 = 0.f, t1 = 0.f;
    if (j < HID) {
        wa = W1[2 * j] * C2L;
        wb = W1[2 * j + 1] * C2L;
        wc = b1[j] * C2L;
        t0 = W2[j];
        t1 = W2[HID + j];
        va = -2.0f * t0;
        vb = -2.0f * t1;
    }
    if (j < 56) {  // zero-pad j=50..55: z=0 -> e=1 -> d=2, va=vb=0 -> no effect
        w[2 * j] = wa;        w[2 * j + 1] = wa;
        w[128 + 2 * j] = wb;  w[128 + 2 * j + 1] = wb;
        w[256 + 2 * j] = wc;  w[256 + 2 * j + 1] = wc;
        w[384 + 2 * j] = va;  w[384 + 2 * j + 1] = va;
        w[512 + 2 * j] = vb;  w[512 + 2 * j + 1] = vb;
    }
#pragma unroll
    for (int off = 32; off > 0; off >>= 1) {
        t0 += __shfl_down(t0, off, 64);
        t1 += __shfl_down(t1, off, 64);
    }
    if (j == 0) { w[640] = b2[0] + t0; w[641] = b2[1] + t1; }
}

__global__ __launch_bounds__(256) void ode_main(const float* __restrict__ y,
                                                const float* __restrict__ w,
                                                float* __restrict__ out) {
    const int tid = blockIdx.x * 256 + threadIdx.x;
    if (tid >= NROWS / 2) return;

    const float4 yv = reinterpret_cast<const float4*>(y)[tid];
    const f32x2 ya = {yv.x, yv.z};   // y[:,0] of rows (2t, 2t+1)
    const f32x2 yb = {yv.y, yv.w};   // y[:,1]

    f32x2 o0 = {w[640], w[640]};
    f32x2 o1 = {w[641], w[641]};

    const f32x2* wa2 = (const f32x2*)(w);
    const f32x2* wb2 = (const f32x2*)(w + 128);
    const f32x2* wc2 = (const f32x2*)(w + 256);
    const f32x2* va2 = (const f32x2*)(w + 384);
    const f32x2* vb2 = (const f32x2*)(w + 512);

    const f32x2 one = {1.0f, 1.0f};

#pragma unroll
    for (int grp = 0; grp < NJ / 4; ++grp) {
        const int j0 = grp * 4;
        f32x2 d0, d1, d2, d3;
        {
            f32x2 z0 = __builtin_elementwise_fma(wa2[j0+0], ya,
                        __builtin_elementwise_fma(wb2[j0+0], yb, wc2[j0+0]));
            f32x2 z1 = __builtin_elementwise_fma(wa2[j0+1], ya,
                        __builtin_elementwise_fma(wb2[j0+1], yb, wc2[j0+1]));
            f32x2 z2 = __builtin_elementwise_fma(wa2[j0+2], ya,
                        __builtin_elementwise_fma(wb2[j0+2], yb, wc2[j0+2]));
            f32x2 z3 = __builtin_elementwise_fma(wa2[j0+3], ya,
                        __builtin_elementwise_fma(wb2[j0+3], yb, wc2[j0+3]));
            f32x2 e0, e1, e2, e3;
            e0.x = __builtin_amdgcn_exp2f(z0.x); e0.y = __builtin_amdgcn_exp2f(z0.y);
            e1.x = __builtin_amdgcn_exp2f(z1.x); e1.y = __builtin_amdgcn_exp2f(z1.y);
            e2.x = __builtin_amdgcn_exp2f(z2.x); e2.y = __builtin_amdgcn_exp2f(z2.y);
            e3.x = __builtin_amdgcn_exp2f(z3.x); e3.y = __builtin_amdgcn_exp2f(z3.y);
            d0 = e0 + one; d1 = e1 + one; d2 = e2 + one; d3 = e3 + one;
        }
        // Montgomery batch inversion: 1 rcp for 4 reciprocals
        f32x2 f1 = d0 * d1;
        f32x2 f2 = f1 * d2;
        f32x2 f3 = f2 * d3;
        f32x2 g;
        g.x = __builtin_amdgcn_rcpf(f3.x);
        g.y = __builtin_amdgcn_rcpf(f3.y);
        f32x2 r3 = f2 * g;  g = g * d3;
        f32x2 r2 = f1 * g;  g = g * d2;
        f32x2 r1 = d0 * g;  g = g * d1;
        f32x2 r0 = g;

        o0 = __builtin_elementwise_fma(va2[j0+0], r0, o0);
        o1 = __builtin_elementwise_fma(vb2[j0+0], r0, o1);
        o0 = __builtin_elementwise_fma(va2[j0+1], r1, o0);
        o1 = __builtin_elementwise_fma(vb2[j0+1], r1, o1);
        o0 = __builtin_elementwise_fma(va2[j0+2], r2, o0);
        o1 = __builtin_elementwise_fma(vb2[j0+2], r2, o1);
        o0 = __builtin_elementwise_fma(va2[j0+3], r3, o0);
        o1 = __builtin_elementwise_fma(vb2[j0+3], r3, o1);
    }

    float4 s; s.x = o0.x; s.y = o1.x; s.z = o0.y; s.w = o1.y;
    reinterpret_cast<float4*>(out)[tid] = s;
}

extern "C" void kernel_launch(void* const* d_in, const int* in_sizes, int n_in,
                              void* d_out, int out_size, void* d_ws, size_t ws_size,
                              hipStream_t stream) {
    // setup_inputs order: t, y, W1, b1, W2, b2
    const float* y  = (const float*)d_in[1];
    const float* W1 = (const float*)d_in[2];
    const float* b1 = (const float*)d_in[3];
    const float* W2 = (const float*)d_in[4];
    const float* b2 = (const float*)d_in[5];
    float* out = (float*)d_out;
    float* w   = (float*)d_ws;   // needs 642 floats; ws is far larger

    prep_kernel<<<1, 64, 0, stream>>>(W1, b1, W2, b2, w);

    const int threads = NROWS / 2;                 // 1,000,000
    const int grid = (threads + 255) / 256;        // 3907
    ode_main<<<grid, 256, 0, stream>>>(y, w, out);
}

// Round 10
// 99.317 us; speedup vs baseline: 1.0565x; 1.0119x over previous
//
#include <hip/hip_runtime.h>

// out = tanh(y @ W1^T + b1) @ W2^T + b2
// y:[B,2] f32, W1:[50,2], b1:[50], W2:[2,50], b2:[2], out:[B,2] f32, B=2e6
//
// Single fused kernel. Wave 0 of every block folds the 252 weights into LDS
// (duplicated pairs for packed-f32 ops), one barrier, then each thread
// processes 2 rows in f32x2 lanes (v_pk_fma_f32).
//   wa[j]=C2L*W1[j][0], wb[j]=C2L*W1[j][1], wc[j]=C2L*b1[j]
//   va[j]=-2*W2[0][j],  vb[j]=-2*W2[1][j]
//   s0=b2[0]+sum W2[0][j], s1=b2[1]+sum W2[1][j]
// tanh(z)=1-2/(exp2(C2L*z)+1): out = s + sum_j v[j]*r_j, r_j=1/(e_j+1).
// Montgomery batch-8 inversion: 2 scalar rcp per 8 j's (was 4-groups).

typedef float f32x2 __attribute__((ext_vector_type(2)));

#define NROWS 2000000
#define HID 50
#define NJ 52                    // 6 groups of 8 + 1 group of 4
#define C2L 2.8853900817779268f  // 2*log2(e)

__global__ __launch_bounds__(256) void ode_fused(const float* __restrict__ y,
                                                 const float* __restrict__ W1,
                                                 const float* __restrict__ b1,
                                                 const float* __restrict__ W2,
                                                 const float* __restrict__ b2,
                                                 float* __restrict__ out) {
    // LDS: wa2[112]@0 | wb2@128 | wc2@256 | va2@384 | vb2@512 | s0,s1@640
    __shared__ float lds[642];

    const int tid = blockIdx.x * 256 + threadIdx.x;

    // ---- fold phase: wave 0 only (lanes 0..63), duplicated writes ----
    if (threadIdx.x < 64) {
        const int j = threadIdx.x;
        float wa = 0.f, wb = 0.f, wc = 0.f, va = 0.f, vb = 0.f;
        float t0 = 0.f, t1 = 0.f;
        if (j < HID) {
            wa = W1[2 * j] * C2L;
            wb = W1[2 * j + 1] * C2L;
            wc = b1[j] * C2L;
            t0 = W2[j];
            t1 = W2[HID + j];
            va = -2.0f * t0;
            vb = -2.0f * t1;
        }
        if (j < NJ) {  // j=50,51 write zeros: e=1 -> d=2, va=vb=0 -> inert
            lds[2 * j] = wa;        lds[2 * j + 1] = wa;
            lds[128 + 2 * j] = wb;  lds[128 + 2 * j + 1] = wb;
            lds[256 + 2 * j] = wc;  lds[256 + 2 * j + 1] = wc;
            lds[384 + 2 * j] = va;  lds[384 + 2 * j + 1] = va;
            lds[512 + 2 * j] = vb;  lds[512 + 2 * j + 1] = vb;
        }
#pragma unroll
        for (int off = 32; off > 0; off >>= 1) {
            t0 += __shfl_down(t0, off, 64);
            t1 += __shfl_down(t1, off, 64);
        }
        if (j == 0) { lds[640] = b2[0] + t0; lds[641] = b2[1] + t1; }
    }
    __syncthreads();

    if (tid >= NROWS / 2) return;

    const float4 yv = reinterpret_cast<const float4*>(y)[tid];
    const f32x2 ya = {yv.x, yv.z};   // y[:,0] of rows (2t, 2t+1)
    const f32x2 yb = {yv.y, yv.w};   // y[:,1]

    f32x2 o0 = {lds[640], lds[640]};
    f32x2 o1 = {lds[641], lds[641]};

    const f32x2* wa2 = (const f32x2*)(lds);
    const f32x2* wb2 = (const f32x2*)(lds + 128);
    const f32x2* wc2 = (const f32x2*)(lds + 256);
    const f32x2* va2 = (const f32x2*)(lds + 384);
    const f32x2* vb2 = (const f32x2*)(lds + 512);

    const f32x2 one = {1.0f, 1.0f};

    // ---- 6 groups of 8: Montgomery batch-8 (1 packed rcp per group) ----
#pragma unroll
    for (int grp = 0; grp < 6; ++grp) {
        const int j0 = grp * 8;
        f32x2 d[8];
#pragma unroll
        for (int k = 0; k < 8; ++k) {
            f32x2 z = __builtin_elementwise_fma(wa2[j0 + k], ya,
                       __builtin_elementwise_fma(wb2[j0 + k], yb, wc2[j0 + k]));
            f32x2 e;
            e.x = __builtin_amdgcn_exp2f(z.x);
            e.y = __builtin_amdgcn_exp2f(z.y);
            d[k] = e + one;
        }
        f32x2 f1 = d[0] * d[1];
        f32x2 f2 = f1 * d[2];
        f32x2 f3 = f2 * d[3];
        f32x2 f4 = f3 * d[4];
        f32x2 f5 = f4 * d[5];
        f32x2 f6 = f5 * d[6];
        f32x2 f7 = f6 * d[7];
        f32x2 g;
        g.x = __builtin_amdgcn_rcpf(f7.x);
        g.y = __builtin_amdgcn_rcpf(f7.y);
        f32x2 r[8];
        r[7] = f6 * g;  g = g * d[7];
        r[6] = f5 * g;  g = g * d[6];
        r[5] = f4 * g;  g = g * d[5];
        r[4] = f3 * g;  g = g * d[4];
        r[3] = f2 * g;  g = g * d[3];
        r[2] = f1 * g;  g = g * d[2];
        r[1] = d[0] * g; g = g * d[1];
        r[0] = g;
#pragma unroll
        for (int k = 0; k < 8; ++k) {
            o0 = __builtin_elementwise_fma(va2[j0 + k], r[k], o0);
            o1 = __builtin_elementwise_fma(vb2[j0 + k], r[k], o1);
        }
    }

    // ---- final group of 4 (j=48..51; 50,51 are inert pads) ----
    {
        const int j0 = 48;
        f32x2 d[4];
#pragma unroll
        for (int k = 0; k < 4; ++k) {
            f32x2 z = __builtin_elementwise_fma(wa2[j0 + k], ya,
                       __builtin_elementwise_fma(wb2[j0 + k], yb, wc2[j0 + k]));
            f32x2 e;
            e.x = __builtin_amdgcn_exp2f(z.x);
            e.y = __builtin_amdgcn_exp2f(z.y);
            d[k] = e + one;
        }
        f32x2 f1 = d[0] * d[1];
        f32x2 f2 = f1 * d[2];
        f32x2 f3 = f2 * d[3];
        f32x2 g;
        g.x = __builtin_amdgcn_rcpf(f3.x);
        g.y = __builtin_amdgcn_rcpf(f3.y);
        f32x2 r[4];
        r[3] = f2 * g;  g = g * d[3];
        r[2] = f1 * g;  g = g * d[2];
        r[1] = d[0] * g; g = g * d[1];
        r[0] = g;
#pragma unroll
        for (int k = 0; k < 4; ++k) {
            o0 = __builtin_elementwise_fma(va2[j0 + k], r[k], o0);
            o1 = __builtin_elementwise_fma(vb2[j0 + k], r[k], o1);
        }
    }

    float4 s; s.x = o0.x; s.y = o1.x; s.z = o0.y; s.w = o1.y;
    reinterpret_cast<float4*>(out)[tid] = s;
}

extern "C" void kernel_launch(void* const* d_in, const int* in_sizes, int n_in,
                              void* d_out, int out_size, void* d_ws, size_t ws_size,
                              hipStream_t stream) {
    // setup_inputs order: t, y, W1, b1, W2, b2
    const float* y  = (const float*)d_in[1];
    const float* W1 = (const float*)d_in[2];
    const float* b1 = (const float*)d_in[3];
    const float* W2 = (const float*)d_in[4];
    const float* b2 = (const float*)d_in[5];
    float* out = (float*)d_out;

    const int threads = NROWS / 2;                 // 1,000,000
    const int grid = (threads + 255) / 256;        // 3907
    ode_fused<<<grid, 256, 0, stream>>>(y, W1, b1, W2, b2, out);
}

// Round 11
// 98.103 us; speedup vs baseline: 1.0696x; 1.0124x over previous
//
#include <hip/hip_runtime.h>

// out = tanh(y @ W1^T + b1) @ W2^T + b2
// y:[B,2] f32, W1:[50,2], b1:[50], W2:[2,50], b2:[2], out:[B,2] f32, B=2e6
//
// Fused single kernel, packed-f32 (2 rows/thread in f32x2 lanes).
// Montgomery batch-4 in TREE form (short dependency chain, small live set)
// + __launch_bounds__(256,8) to force VGPR<=64 -> 8 waves/SIMD residency.
// LDS layout: per 4-j group, 40 contiguous duplicated floats
//   [wa0,wa0,wa1,wa1,wa2,wa2,wa3,wa3 | wb.. | wc.. | va.. | vb..]
// so weight loads merge into ds_read_b128 (130 LDS ops vs 260).
// tanh(z)=1-2/(exp2(C2L*z)+1): out = s + sum_j v[j]*r_j, r_j=1/(e_j+1).

typedef float f32x2 __attribute__((ext_vector_type(2)));

#define NROWS 2000000
#define HID 50
#define NGRP 13                  // 13 groups of 4 j's = 52 (j=50,51 inert pads)
#define C2L 2.8853900817779268f  // 2*log2(e)

__global__ __launch_bounds__(256, 8) void ode_fused(const float* __restrict__ y,
                                                    const float* __restrict__ W1,
                                                    const float* __restrict__ b1,
                                                    const float* __restrict__ W2,
                                                    const float* __restrict__ b2,
                                                    float* __restrict__ out) {
    __shared__ float lds[NGRP * 40 + 2];   // 522 floats

    const int tid = blockIdx.x * 256 + threadIdx.x;

    // ---- fold phase: wave 0 only ----
    if (threadIdx.x < 64) {
        const int j = threadIdx.x;
        float wa = 0.f, wb = 0.f, wc = 0.f, va = 0.f, vb = 0.f;
        float t0 = 0.f, t1 = 0.f;
        if (j < HID) {
            wa = W1[2 * j] * C2L;
            wb = W1[2 * j + 1] * C2L;
            wc = b1[j] * C2L;
            t0 = W2[j];
            t1 = W2[HID + j];
            va = -2.0f * t0;
            vb = -2.0f * t1;
        }
        if (j < NGRP * 4) {  // j=50,51 -> zeros: d=2, va=vb=0 -> inert
            const int base = (j >> 2) * 40 + 2 * (j & 3);
            lds[base +  0] = wa; lds[base +  1] = wa;
            lds[base +  8] = wb; lds[base +  9] = wb;
            lds[base + 16] = wc; lds[base + 17] = wc;
            lds[base + 24] = va; lds[base + 25] = va;
            lds[base + 32] = vb; lds[base + 33] = vb;
        }
#pragma unroll
        for (int off = 32; off > 0; off >>= 1) {
            t0 += __shfl_down(t0, off, 64);
            t1 += __shfl_down(t1, off, 64);
        }
        if (j == 0) { lds[NGRP * 40] = b2[0] + t0; lds[NGRP * 40 + 1] = b2[1] + t1; }
    }
    __syncthreads();

    if (tid >= NROWS / 2) return;

    const float4 yv = reinterpret_cast<const float4*>(y)[tid];
    const f32x2 ya = {yv.x, yv.z};   // y[:,0] of rows (2t, 2t+1)
    const f32x2 yb = {yv.y, yv.w};   // y[:,1]

    f32x2 o0 = {lds[NGRP * 40], lds[NGRP * 40]};
    f32x2 o1 = {lds[NGRP * 40 + 1], lds[NGRP * 40 + 1]};

    const f32x2 one = {1.0f, 1.0f};

#pragma unroll
    for (int g = 0; g < NGRP; ++g) {
        const float4* Q = (const float4*)(lds + g * 40);
        const float4 A0 = Q[0], A1 = Q[1];   // wa pairs j0..j3
        const float4 B0 = Q[2], B1 = Q[3];   // wb
        const float4 C0 = Q[4], C1 = Q[5];   // wc
        const float4 V0 = Q[6], V1 = Q[7];   // va
        const float4 U0 = Q[8], U1 = Q[9];   // vb

        f32x2 z0 = __builtin_elementwise_fma((f32x2){A0.x, A0.y}, ya,
                    __builtin_elementwise_fma((f32x2){B0.x, B0.y}, yb, (f32x2){C0.x, C0.y}));
        f32x2 z1 = __builtin_elementwise_fma((f32x2){A0.z, A0.w}, ya,
                    __builtin_elementwise_fma((f32x2){B0.z, B0.w}, yb, (f32x2){C0.z, C0.w}));
        f32x2 z2 = __builtin_elementwise_fma((f32x2){A1.x, A1.y}, ya,
                    __builtin_elementwise_fma((f32x2){B1.x, B1.y}, yb, (f32x2){C1.x, C1.y}));
        f32x2 z3 = __builtin_elementwise_fma((f32x2){A1.z, A1.w}, ya,
                    __builtin_elementwise_fma((f32x2){B1.z, B1.w}, yb, (f32x2){C1.z, C1.w}));

        f32x2 d0, d1, d2, d3;
        d0.x = __builtin_amdgcn_exp2f(z0.x); d0.y = __builtin_amdgcn_exp2f(z0.y);
        d1.x = __builtin_amdgcn_exp2f(z1.x); d1.y = __builtin_amdgcn_exp2f(z1.y);
        d2.x = __builtin_amdgcn_exp2f(z2.x); d2.y = __builtin_amdgcn_exp2f(z2.y);
        d3.x = __builtin_amdgcn_exp2f(z3.x); d3.y = __builtin_amdgcn_exp2f(z3.y);
        d0 = d0 + one; d1 = d1 + one; d2 = d2 + one; d3 = d3 + one;

        // Montgomery batch-4, tree form (depth ~4, 9 muls, 1 packed rcp)
        f32x2 p01 = d0 * d1;
        f32x2 p23 = d2 * d3;
        f32x2 f = p01 * p23;
        f32x2 gg;
        gg.x = __builtin_amdgcn_rcpf(f.x);
        gg.y = __builtin_amdgcn_rcpf(f.y);
        f32x2 g01 = gg * p23;   // 1/(d0*d1)
        f32x2 g23 = gg * p01;   // 1/(d2*d3)
        f32x2 r0 = g01 * d1;
        f32x2 r1 = g01 * d0;
        f32x2 r2 = g23 * d3;
        f32x2 r3 = g23 * d2;

        o0 = __builtin_elementwise_fma((f32x2){V0.x, V0.y}, r0, o0);
        o1 = __builtin_elementwise_fma((f32x2){U0.x, U0.y}, r0, o1);
        o0 = __builtin_elementwise_fma((f32x2){V0.z, V0.w}, r1, o0);
        o1 = __builtin_elementwise_fma((f32x2){U0.z, U0.w}, r1, o1);
        o0 = __builtin_elementwise_fma((f32x2){V1.x, V1.y}, r2, o0);
        o1 = __builtin_elementwise_fma((f32x2){U1.x, U1.y}, r2, o1);
        o0 = __builtin_elementwise_fma((f32x2){V1.z, V1.w}, r3, o0);
        o1 = __builtin_elementwise_fma((f32x2){U1.z, U1.w}, r3, o1);
    }

    float4 s; s.x = o0.x; s.y = o1.x; s.z = o0.y; s.w = o1.y;
    reinterpret_cast<float4*>(out)[tid] = s;
}

extern "C" void kernel_launch(void* const* d_in, const int* in_sizes, int n_in,
                              void* d_out, int out_size, void* d_ws, size_t ws_size,
                              hipStream_t stream) {
    // setup_inputs order: t, y, W1, b1, W2, b2
    const float* y  = (const float*)d_in[1];
    const float* W1 = (const float*)d_in[2];
    const float* b1 = (const float*)d_in[3];
    const float* W2 = (const float*)d_in[4];
    const float* b2 = (const float*)d_in[5];
    float* out = (float*)d_out;

    const int threads = NROWS / 2;                 // 1,000,000
    const int grid = (threads + 255) / 256;        // 3907
    ode_fused<<<grid, 256, 0, stream>>>(y, W1, b1, W2, b2, out);
}